// Round 2
// 527.123 us; speedup vs baseline: 1.0785x; 1.0785x over previous
//
#include <hip/hip_runtime.h>
#include <math.h>

typedef unsigned int u32;

#define NROWS 500000
#define NCLS  100
#define NBINS 15
#define NRANK 31
#define NSLOT 32
#define TROWS 64
#define HISTB 128

#define NEG_INF (-__builtin_inff())

// ---- workspace byte offsets ----
#define OFF_CONF_T 0
#define OFF_CONF_S 2000000
#define OFF_WPER   4000000
// zeroed span: [OFF_CHIST, OFF_ZEND)
#define OFF_CHIST  6000128                 // 65536 u32 coarse hist (top-16 bits of conf)
#define OFF_SHIST  (OFF_CHIST + 262144)    // 32 * 65536 u32 second-level hists
#define OFF_ACC    (OFF_SHIST + 8388608)   // wnum f32[15] @+0, cnt i32[15] @+64, perbin f32[15] @+128, fedges f32[16] @+192
#define OFF_SMAP   (OFF_ACC + 256)         // 65536 int: coarse bin -> slot+1, 0 = none (pre-zeroed)
#define OFF_ZEND   (OFF_SMAP + 262144)
// not zeroed (fully overwritten):
#define OFF_META   OFF_ZEND                // ints: [0..30] bin, [32..62] resid, [64..94] slot, [96] nslots
#define OFF_VALS   (OFF_META + 512)        // 31 floats (order statistics)
#define OFF_EDGES  (OFF_VALS + 128)        // 16 doubles (kept for reference/debug)
#define OFF_CE     (OFF_EDGES + 128)       // 15 doubles

__global__ __launch_bounds__(256) void zero_kernel(u32* __restrict__ p, int n) {
    int i = blockIdx.x * 256 + threadIdx.x;
    if (i < n) p[i] = 0u;
}

// ---- conf kernel: global_load_lds staging, 64 rows/block, 4 lanes/row ----
// lane qd handles float4 columns j in {qd, qd+4, ..., <=24}. max-only (no argmax);
// source rows recover pred==label via logits[label]==rowmax (ties ~1e-9 on gaussian data).
__global__ __launch_bounds__(256) void conf_kernel(
    const float* __restrict__ logits_t, const float* __restrict__ logits_s,
    const int* __restrict__ labels, const float* __restrict__ weight,
    float* __restrict__ conf_t, float* __restrict__ conf_s,
    float* __restrict__ wper, int tb)
{
    __shared__ __align__(16) float tile[TROWS * NCLS];   // 25.6 KB -> 6 blocks/CU
    int t = threadIdx.x;
    bool is_src = (int)blockIdx.x >= tb;
    int bid = is_src ? (int)blockIdx.x - tb : (int)blockIdx.x;
    const float* logits = is_src ? logits_s : logits_t;
    int tile0 = bid * TROWS;
    int rows = NROWS - tile0; if (rows > TROWS) rows = TROWS;
    const float4* gp = (const float4*)(logits + (size_t)tile0 * NCLS);
    int wv = t >> 6, ln = t & 63;

    if (rows == TROWS) {
        // full tile: direct global->LDS, width 16, linear layout.
        // guard is wave-uniform here (1600 = 6*256 + 64).
        #pragma unroll
        for (int k = 0; k < 7; ++k) {
            int idx = k * 256 + wv * 64 + ln;
            if (idx < TROWS * 25) {
                __builtin_amdgcn_global_load_lds(
                    (const __attribute__((address_space(1))) u32*)(gp + idx),
                    (__attribute__((address_space(3))) u32*)(&tile[(k * 256 + wv * 64) * 4]),
                    16, 0, 0);
            }
        }
    } else {
        // partial last tile (2 blocks total): safe VGPR round-trip staging
        int nf4 = rows * 25;
        for (int idx = t; idx < nf4; idx += 256) {
            float4 v = gp[idx];
            *(float4*)&tile[idx * 4] = v;
        }
    }
    __syncthreads();   // drains vmcnt/lgkmcnt before use

    int r = t >> 2, qd = t & 3;
    const float* rp = &tile[r * NCLS];
    float4 x[7];
    #pragma unroll
    for (int k = 0; k < 6; ++k)
        x[k] = *(const float4*)(rp + (qd + 4 * k) * 4);
    x[6] = (qd == 0) ? *(const float4*)(rp + 96)
                     : make_float4(NEG_INF, NEG_INF, NEG_INF, NEG_INF);

    float4 m4 = x[0];
    #pragma unroll
    for (int k = 1; k < 7; ++k) {
        m4.x = fmaxf(m4.x, x[k].x); m4.y = fmaxf(m4.y, x[k].y);
        m4.z = fmaxf(m4.z, x[k].z); m4.w = fmaxf(m4.w, x[k].w);
    }
    float m = fmaxf(fmaxf(m4.x, m4.y), fmaxf(m4.z, m4.w));
    m = fmaxf(m, __shfl_xor(m, 1));
    m = fmaxf(m, __shfl_xor(m, 2));   // row max in all 4 lanes

    float sx = 0.f, sy = 0.f, sz = 0.f, sw = 0.f;
    #pragma unroll
    for (int k = 0; k < 7; ++k) {
        sx += __expf(x[k].x - m); sy += __expf(x[k].y - m);
        sz += __expf(x[k].z - m); sw += __expf(x[k].w - m);   // __expf(-inf)=0 for pad
    }
    float s = (sx + sy) + (sz + sw);
    s += __shfl_xor(s, 1);
    s += __shfl_xor(s, 2);

    if (qd == 0 && r < rows) {
        float c = 1.0f / s;
        int row = tile0 + r;
        if (is_src) {
            conf_s[row] = c;
            int lab = labels[row];
            wper[row] = (rp[lab] == m) ? weight[lab] : 0.0f;
        } else {
            conf_t[row] = c;
        }
    }
}

// coarse histogram of conf_t top-16 bits with LDS privatization.
__global__ __launch_bounds__(256) void hist_kernel(
    const float* __restrict__ conf, u32* __restrict__ chist)
{
    __shared__ u32 h[1024];
    int t = threadIdx.x;
    for (int i = t; i < 1024; i += 256) h[i] = 0u;
    __syncthreads();
    for (int i = blockIdx.x * 256 + t; i < NROWS; i += HISTB * 256) {
        u32 b = __float_as_uint(conf[i]) >> 16;
        u32 u = b - 15360u;
        if (u < 1024u) atomicAdd(&h[u], 1u);
        else atomicAdd(&chist[b], 1u);   // safety net; mathematically unreachable
    }
    __syncthreads();
    for (int i = t; i < 1024; i += 256) {
        u32 v = h[i];
        if (v) atomicAdd(&chist[15360 + i], v);
    }
}

// ranks needed: for k=0..14: i_k=floor(k*500000/15) and i_k+1 (q=2k,2k+1); q=30 -> N-1
__device__ __forceinline__ int rank_of(int q) {
    if (q == NRANK - 1) return NROWS - 1;
    int k = q >> 1;
    int ik = (int)(((long long)k * 100000) / 3);
    return ik + (q & 1);
}

// 1024-thread block: block scan over coarse hist, binary-search locate, chunk walk.
// smap is pre-zeroed by zero_kernel; we only write the <=31 used entries (slot+1).
__global__ __launch_bounds__(1024) void rank_prep_kernel(
    const u32* __restrict__ chist, int* __restrict__ smap, int* __restrict__ meta)
{
    __shared__ u32 pre[1024];
    __shared__ u32 wtot[16];
    __shared__ int s_cq[NRANK], s_res[NRANK], s_bin[NRANK];
    __shared__ u32 cd[NRANK * 64];
    __shared__ int s_slotbin[NSLOT];
    __shared__ int s_ns;
    int t = threadIdx.x;
    const uint4* hp = (const uint4*)chist;
    u32 csum = 0;
    for (int j = 0; j < 16; ++j) { uint4 v = hp[t * 16 + j]; csum += v.x + v.y + v.z + v.w; }
    u32 x = csum;
    for (int off = 1; off < 64; off <<= 1) { u32 y = __shfl_up(x, off); if ((t & 63) >= off) x += y; }
    int wv = t >> 6;
    if ((t & 63) == 63) wtot[wv] = x;
    __syncthreads();
    if (t == 0) { u32 run = 0; for (int w = 0; w < 16; ++w) { u32 v = wtot[w]; wtot[w] = run; run += v; } }
    __syncthreads();
    pre[t] = x - csum + wtot[wv];
    __syncthreads();
    if (t < NRANK) {
        u32 r = (u32)rank_of(t);
        int lo = 0, hi = 1023;
        while (lo < hi) { int mid = (lo + hi + 1) >> 1; if (pre[mid] <= r) lo = mid; else hi = mid - 1; }
        s_cq[t] = lo;
        s_res[t] = (int)(r - pre[lo]);
    }
    __syncthreads();
    for (int idx = t; idx < NRANK * 64; idx += 1024) {
        int q = idx >> 6, j = idx & 63;
        cd[idx] = chist[s_cq[q] * 64 + j];
    }
    __syncthreads();
    if (t < NRANK) {
        u32 run = 0; u32 res = (u32)s_res[t]; int bin = 0;
        for (int j = 0; j < 64; ++j) {
            u32 h = cd[t * 64 + j];
            if (res < run + h) { bin = s_cq[t] * 64 + j; s_res[t] = (int)(res - run); break; }
            run += h;
        }
        s_bin[t] = bin;
    }
    __syncthreads();
    if (t == 0) {
        int ns = 0;
        for (int q = 0; q < NRANK; ++q) {
            int b = s_bin[q], sl = -1;
            for (int u = 0; u < ns; ++u) if (s_slotbin[u] == b) { sl = u; break; }
            if (sl < 0) { sl = ns; s_slotbin[ns++] = b; }
            meta[q] = b; meta[32 + q] = s_res[q]; meta[64 + q] = sl;
        }
        s_ns = ns; meta[96] = ns;
    }
    __syncthreads();
    if (t < s_ns) smap[s_slotbin[t]] = t + 1;   // O(1) writes; smap pre-zeroed
}

__global__ __launch_bounds__(256) void slot_hist_kernel(
    const float* __restrict__ conf, const int* __restrict__ smap, u32* __restrict__ shist)
{
    int i = blockIdx.x * 256 + threadIdx.x;
    if (i >= NROWS) return;
    u32 b = __float_as_uint(conf[i]);
    int sl = smap[b >> 16] - 1;   // 0 = none
    if (sl >= 0) atomicAdd(&shist[(size_t)sl * 65536 + (b & 0xFFFFu)], 1u);
}

// one block per rank: block scan over the slot's 65536-bin hist, LDS chunk walk
__global__ __launch_bounds__(1024) void select_kernel(
    const u32* __restrict__ shist, const int* __restrict__ meta, float* __restrict__ vals)
{
    __shared__ u32 wtot[16];
    __shared__ int s_chunk; __shared__ u32 s_base;
    __shared__ u32 cd[64];
    int q = blockIdx.x, t = threadIdx.x;
    int sl = meta[64 + q]; u32 res = (u32)meta[32 + q]; int bin = meta[q];
    const u32* h = shist + (size_t)sl * 65536;
    const uint4* hp = (const uint4*)h;
    u32 csum = 0;
    for (int j = 0; j < 16; ++j) { uint4 v = hp[t * 16 + j]; csum += v.x + v.y + v.z + v.w; }
    u32 x = csum;
    for (int off = 1; off < 64; off <<= 1) { u32 y = __shfl_up(x, off); if ((t & 63) >= off) x += y; }
    int wv = t >> 6;
    if ((t & 63) == 63) wtot[wv] = x;
    __syncthreads();
    if (t == 0) { u32 run = 0; for (int w = 0; w < 16; ++w) { u32 v = wtot[w]; wtot[w] = run; run += v; } }
    __syncthreads();
    u32 prex = x - csum + wtot[wv];
    if (res >= prex && res < prex + csum) { s_chunk = t; s_base = prex; }
    __syncthreads();
    int c = s_chunk;
    if (t < 64) cd[t] = h[c * 64 + t];
    __syncthreads();
    if (t == 0) {
        u32 run = s_base; int low = 0;
        for (int j = 0; j < 64; ++j) {
            u32 hh = cd[j];
            if (res < run + hh) { low = c * 64 + j; break; }
            run += hh;
        }
        vals[q] = __uint_as_float(((u32)bin << 16) | (u32)low);
    }
}

// parallel over 16 edges; also emits round-DOWN float edges so all later
// binning compares in f32: for float c, (c > e_double) <=> (c > floor_to_float(e)).
__global__ void edges_kernel(const float* __restrict__ vals, double* __restrict__ edges,
                             float* __restrict__ fedges) {
    int k = threadIdx.x;
    if (k < 16) {
        double e;
        if (k == 0)       e = (double)vals[0];
        else if (k == 15) e = (double)vals[30];
        else {
            double step = (double)NROWS / 15.0;
            long long ik = ((long long)k * 100000) / 3;
            double frac = (double)k * step - (double)ik;
            double a = (double)vals[2 * k];
            double b = (double)vals[2 * k + 1];
            e = a + frac * (b - a);
        }
        edges[k] = e;
        float f = (float)e;                                   // round-to-nearest
        if ((double)f > e) f = __uint_as_float(__float_as_uint(f) - 1u);  // force round-down (e > 0)
        fedges[k] = f;
    }
}

// bin = (#edges strictly < conf) - 1; valid if in [0,14]. f32 compares (exact, see edges_kernel).
__global__ __launch_bounds__(256) void bin_accum_kernel(
    const float* __restrict__ conf_s, const float* __restrict__ wper,
    const float* __restrict__ conf_t, const float* __restrict__ fedges,
    float* __restrict__ g_wnum, int* __restrict__ g_cnt)
{
    __shared__ float l_w[NBINS];
    __shared__ int   l_c[NBINS];
    int t = threadIdx.x;
    if (t < NBINS) { l_w[t] = 0.0f; l_c[t] = 0; }
    __syncthreads();
    float e[16];
    #pragma unroll
    for (int j = 0; j < 16; ++j) e[j] = fedges[j];
    int i = blockIdx.x * 256 + t;
    if (i < NROWS) {
        float c = conf_s[i];
        int cnt = 0;
        #pragma unroll
        for (int j = 0; j < 16; ++j) cnt += (c > e[j]) ? 1 : 0;
        if (cnt >= 1 && cnt <= NBINS) {
            float w = wper[i];
            if (w != 0.0f) atomicAdd(&l_w[cnt - 1], w);
        }
    } else if (i < 2 * NROWS) {
        float c = conf_t[i - NROWS];
        int cnt = 0;
        #pragma unroll
        for (int j = 0; j < 16; ++j) cnt += (c > e[j]) ? 1 : 0;
        if (cnt >= 1 && cnt <= NBINS) atomicAdd(&l_c[cnt - 1], 1);
    }
    __syncthreads();
    if (t < NBINS) {
        float w = l_w[t];
        int cc = l_c[t];
        if (w != 0.0f) atomicAdd(&g_wnum[t], w);
        if (cc) atomicAdd(&g_cnt[t], cc);
    }
}

__global__ void cond_kernel(const float* __restrict__ g_wnum, const int* __restrict__ g_cnt,
                            double* __restrict__ ce)
{
    int t = threadIdx.x;
    if (t < NBINS) {
        int d = g_cnt[t] - 1; if (d < 1) d = 1;
        ce[t] = ((double)(NROWS - 1) / (double)NROWS) * (double)g_wnum[t] / (double)d;
    }
}

__global__ __launch_bounds__(256) void diff_kernel(
    const float* __restrict__ conf_t, const float* __restrict__ fedges,
    const double* __restrict__ ce, float* __restrict__ g_perbin)
{
    __shared__ float l_p[NBINS];
    int t = threadIdx.x;
    if (t < NBINS) l_p[t] = 0.0f;
    __syncthreads();
    float e[16];
    #pragma unroll
    for (int j = 0; j < 16; ++j) e[j] = fedges[j];
    int i = blockIdx.x * 256 + t;
    if (i < NROWS) {
        float c = conf_t[i];
        int cnt = 0;
        #pragma unroll
        for (int j = 0; j < 16; ++j) cnt += (c > e[j]) ? 1 : 0;
        if (cnt >= 1 && cnt <= NBINS) {
            double d = (double)c - ce[cnt - 1];
            atomicAdd(&l_p[cnt - 1], (float)(d * d));
        }
    }
    __syncthreads();
    if (t < NBINS) {
        float p = l_p[t];
        if (p != 0.0f) atomicAdd(&g_perbin[t], p);
    }
}

__global__ void final_kernel(const float* __restrict__ g_perbin, const int* __restrict__ g_cnt,
                             float* __restrict__ out)
{
    if (threadIdx.x == 0 && blockIdx.x == 0) {
        double ssum = 0.0;
        for (int b = 0; b < NBINS; ++b)
            if (g_cnt[b] > 1) ssum += (double)g_perbin[b];
        out[0] = (float)(ssum / (double)NROWS);
    }
}

extern "C" void kernel_launch(void* const* d_in, const int* in_sizes, int n_in,
                              void* d_out, int out_size, void* d_ws, size_t ws_size,
                              hipStream_t stream)
{
    const float* logits_s = (const float*)d_in[0];
    const int*   labels   = (const int*)d_in[1];
    const float* logits_t = (const float*)d_in[2];
    const float* weight   = (const float*)d_in[3];

    char* ws = (char*)d_ws;
    float*  conf_t   = (float*)(ws + OFF_CONF_T);
    float*  conf_s   = (float*)(ws + OFF_CONF_S);
    float*  wper     = (float*)(ws + OFF_WPER);
    u32*    chist    = (u32*)(ws + OFF_CHIST);
    u32*    shist    = (u32*)(ws + OFF_SHIST);
    int*    smap     = (int*)(ws + OFF_SMAP);
    int*    meta     = (int*)(ws + OFF_META);
    float*  vals     = (float*)(ws + OFF_VALS);
    double* edges    = (double*)(ws + OFF_EDGES);
    double* ce       = (double*)(ws + OFF_CE);
    float*  g_wnum   = (float*)(ws + OFF_ACC);
    int*    g_cnt    = (int*)(ws + OFF_ACC + 64);
    float*  g_perbin = (float*)(ws + OFF_ACC + 128);
    float*  fedges   = (float*)(ws + OFF_ACC + 192);
    float*  out      = (float*)d_out;

    int zwords = (OFF_ZEND - OFF_CHIST) / 4;
    zero_kernel<<<(zwords + 255) / 256, 256, 0, stream>>>((u32*)(ws + OFF_CHIST), zwords);

    int tb = (NROWS + TROWS - 1) / TROWS;      // 7813 tiles of 64 rows
    int gb = (NROWS + 255) / 256;
    conf_kernel<<<2 * tb, 256, 0, stream>>>(logits_t, logits_s, labels, weight,
                                            conf_t, conf_s, wper, tb);
    hist_kernel<<<HISTB, 256, 0, stream>>>(conf_t, chist);
    rank_prep_kernel<<<1, 1024, 0, stream>>>(chist, smap, meta);
    slot_hist_kernel<<<gb, 256, 0, stream>>>(conf_t, smap, shist);
    select_kernel<<<NRANK, 1024, 0, stream>>>(shist, meta, vals);
    edges_kernel<<<1, 64, 0, stream>>>(vals, edges, fedges);
    bin_accum_kernel<<<(2 * NROWS + 255) / 256, 256, 0, stream>>>(conf_s, wper, conf_t, fedges, g_wnum, g_cnt);
    cond_kernel<<<1, 64, 0, stream>>>(g_wnum, g_cnt, ce);
    diff_kernel<<<gb, 256, 0, stream>>>(conf_t, fedges, ce, g_perbin);
    final_kernel<<<1, 64, 0, stream>>>(g_perbin, g_cnt, out);
}